// Round 1
// baseline (4770.834 us; speedup 1.0000x reference)
//
#include <hip/hip_runtime.h>
#include <hip/hip_bf16.h>
#include <math.h>

#define N_NODES 50000
#define N_EDGES 600000
#define HDIM    128
#define NLAYERS 4
#define NGRAPH  256

// ------------------------------------------------------------------
// GEMM: C[M x NC] = A[M x 128] @ B[128 x NC] + bias[NC]
// BM=64, BN=64, BK=32, 256 threads, 4x4 micro-tile per thread.
// ------------------------------------------------------------------
__global__ __launch_bounds__(256) void gemm_k128(
    const float* __restrict__ A, const float* __restrict__ B,
    const float* __restrict__ bias, float* __restrict__ C,
    int M, int NC)
{
    __shared__ float As[32][65];   // [k][m], +1 pad to break store conflicts
    __shared__ float Bs[32][64];   // [k][n]

    const int tid = threadIdx.x;
    const int tx = tid & 15, ty = tid >> 4;
    const int row0 = blockIdx.x * 64;
    const int col0 = blockIdx.y * 64;

    float acc[4][4];
#pragma unroll
    for (int i = 0; i < 4; i++)
#pragma unroll
        for (int j = 0; j < 4; j++) acc[i][j] = 0.f;

    for (int k0 = 0; k0 < 128; k0 += 32) {
        // A tile: 64 rows x 32 k  (512 float4, 2 per thread)
#pragma unroll
        for (int u = 0; u < 2; u++) {
            int idx = tid + u * 256;          // 0..511
            int m   = idx >> 3;               // row within tile
            int k4  = (idx & 7) << 2;         // k offset (x4)
            int row = row0 + m;
            if (row >= M) row = M - 1;        // clamp (stores are guarded)
            const float4 av = *(const float4*)(A + (size_t)row * 128 + k0 + k4);
            As[k4 + 0][m] = av.x;
            As[k4 + 1][m] = av.y;
            As[k4 + 2][m] = av.z;
            As[k4 + 3][m] = av.w;
        }
        // B tile: 32 k x 64 cols (512 float4, 2 per thread)
#pragma unroll
        for (int u = 0; u < 2; u++) {
            int idx = tid + u * 256;
            int k   = idx >> 4;
            int n4  = (idx & 15) << 2;
            const float4 bv = *(const float4*)(B + (size_t)(k0 + k) * NC + col0 + n4);
            *(float4*)&Bs[k][n4] = bv;
        }
        __syncthreads();
#pragma unroll
        for (int k = 0; k < 32; k++) {
            float a0 = As[k][ty * 4 + 0];
            float a1 = As[k][ty * 4 + 1];
            float a2 = As[k][ty * 4 + 2];
            float a3 = As[k][ty * 4 + 3];
            float b0 = Bs[k][tx * 4 + 0];
            float b1 = Bs[k][tx * 4 + 1];
            float b2 = Bs[k][tx * 4 + 2];
            float b3 = Bs[k][tx * 4 + 3];
            acc[0][0] += a0 * b0; acc[0][1] += a0 * b1; acc[0][2] += a0 * b2; acc[0][3] += a0 * b3;
            acc[1][0] += a1 * b0; acc[1][1] += a1 * b1; acc[1][2] += a1 * b2; acc[1][3] += a1 * b3;
            acc[2][0] += a2 * b0; acc[2][1] += a2 * b1; acc[2][2] += a2 * b2; acc[2][3] += a2 * b3;
            acc[3][0] += a3 * b0; acc[3][1] += a3 * b1; acc[3][2] += a3 * b2; acc[3][3] += a3 * b3;
        }
        __syncthreads();
    }

    // epilogue: bias + store (float4 per row)
#pragma unroll
    for (int i = 0; i < 4; i++) {
        int row = row0 + ty * 4 + i;
        if (row < M) {
            int col = col0 + tx * 4;
            float4 bv = *(const float4*)(bias + col);
            float4 cv;
            cv.x = acc[i][0] + bv.x;
            cv.y = acc[i][1] + bv.y;
            cv.z = acc[i][2] + bv.z;
            cv.w = acc[i][3] + bv.w;
            *(float4*)(C + (size_t)row * NC + col) = cv;
        }
    }
}

// ------------------------------------------------------------------
// Build concatenated weights: Wcat[l] is [128 x 512]:
//   cols   0-127 : Wg[l][0:128]    (gate, receiver half)   bias = bg[l]
//   cols 128-255 : Wg[l][128:256]  (gate, sender half)     bias = 0
//   cols 256-383 : Ws[l]                                   bias = bs[l]
//   cols 384-511 : Wr[l]                                   bias = br[l]
// ------------------------------------------------------------------
__global__ void build_wcat(const float* __restrict__ Wg, const float* __restrict__ Ws,
                           const float* __restrict__ Wr, const float* __restrict__ bg,
                           const float* __restrict__ bs, const float* __restrict__ br,
                           float* __restrict__ wcat, float* __restrict__ bcat)
{
    int t = blockIdx.x * blockDim.x + threadIdx.x;
    if (t >= NLAYERS * 128 * 512) return;
    int l = t >> 16;
    int r = t & 65535;
    int k = r >> 9;
    int c = r & 511;
    float v;
    if (c < 128)      v = Wg[l * 32768 + k * 128 + c];
    else if (c < 256) v = Wg[l * 32768 + (128 + k) * 128 + (c - 128)];
    else if (c < 384) v = Ws[l * 16384 + k * 128 + (c - 256)];
    else              v = Wr[l * 16384 + k * 128 + (c - 384)];
    wcat[t] = v;
    if (k == 0) {
        float b;
        if (c < 128)      b = bg[l * 128 + c];
        else if (c < 256) b = 0.f;
        else if (c < 384) b = bs[l * 128 + (c - 256)];
        else              b = br[l * 128 + (c - 384)];
        bcat[l * 512 + c] = b;
    }
}

// ------------------------------------------------------------------
// Edge phase: for edge e (send -> rec):
//   eta = sigmoid(g_r[rec] + g_s[send])      (bg folded into g_r bias)
//   msg = eta * s[send]                      (bs folded into s)
//   atomicAdd(big[rec][384..512], msg)       (r = h@Wr+br pre-seeded there)
// 32 lanes per edge, float4 per lane.
// ------------------------------------------------------------------
__global__ __launch_bounds__(256) void edge_kernel(
    const int* __restrict__ ei,   // [2][E]: row0 = send, row1 = rec
    float* __restrict__ big)      // [N][512]
{
    int t = blockIdx.x * blockDim.x + threadIdx.x;
    int e = t >> 5;
    int lane = t & 31;
    if (e >= N_EDGES) return;
    int send = ei[e];
    int rec  = ei[N_EDGES + e];
    const float4 gr = *(const float4*)(big + (size_t)rec  * 512 +   0 + lane * 4);
    const float4 gs = *(const float4*)(big + (size_t)send * 512 + 128 + lane * 4);
    const float4 sv = *(const float4*)(big + (size_t)send * 512 + 256 + lane * 4);
    float4 m;
    m.x = sv.x / (1.f + __expf(-(gr.x + gs.x)));
    m.y = sv.y / (1.f + __expf(-(gr.y + gs.y)));
    m.z = sv.z / (1.f + __expf(-(gr.z + gs.z)));
    m.w = sv.w / (1.f + __expf(-(gr.w + gs.w)));
    float* dst = big + (size_t)rec * 512 + 384 + lane * 4;
    unsafeAtomicAdd(dst + 0, m.x);
    unsafeAtomicAdd(dst + 1, m.y);
    unsafeAtomicAdd(dst + 2, m.z);
    unsafeAtomicAdd(dst + 3, m.w);
}

// ------------------------------------------------------------------
// h = h + relu(r + agg)   (both live in big cols 384..512)
// ------------------------------------------------------------------
__global__ __launch_bounds__(256) void update_kernel(
    float* __restrict__ h, const float* __restrict__ big)
{
    int t = blockIdx.x * blockDim.x + threadIdx.x;
    if (t >= N_NODES * 32) return;
    int n = t >> 5;
    int j4 = (t & 31) * 4;
    float4 hv = *(float4*)(h + (size_t)n * 128 + j4);
    float4 av = *(const float4*)(big + (size_t)n * 512 + 384 + j4);
    hv.x += fmaxf(av.x, 0.f);
    hv.y += fmaxf(av.y, 0.f);
    hv.z += fmaxf(av.z, 0.f);
    hv.w += fmaxf(av.w, 0.f);
    *(float4*)(h + (size_t)n * 128 + j4) = hv;
}

// ------------------------------------------------------------------
// Global add pool: hagg[batch[n]] += h[n]
// ------------------------------------------------------------------
__global__ __launch_bounds__(256) void pool_kernel(
    const float* __restrict__ h, const int* __restrict__ batch,
    float* __restrict__ hagg)
{
    int t = blockIdx.x * blockDim.x + threadIdx.x;
    if (t >= N_NODES * 32) return;
    int n = t >> 5;
    int j4 = (t & 31) * 4;
    int g = batch[n];
    const float4 hv = *(const float4*)(h + (size_t)n * 128 + j4);
    float* dst = hagg + (size_t)g * 128 + j4;
    unsafeAtomicAdd(dst + 0, hv.x);
    unsafeAtomicAdd(dst + 1, hv.y);
    unsafeAtomicAdd(dst + 2, hv.z);
    unsafeAtomicAdd(dst + 3, hv.w);
}

// ------------------------------------------------------------------
// Head: out[g] = relu(hagg[g] @ W1 + b1) @ W2 + b2
// one block (64 threads = 1 wave) per graph
// ------------------------------------------------------------------
__global__ __launch_bounds__(64) void head_kernel(
    const float* __restrict__ hagg, const float* __restrict__ W1,
    const float* __restrict__ b1, const float* __restrict__ W2,
    const float* __restrict__ b2, float* __restrict__ out)
{
    int g = blockIdx.x;
    int j = threadIdx.x;           // 0..63 hidden unit
    float acc = b1[j];
    for (int k = 0; k < 128; k++)
        acc += hagg[(size_t)g * 128 + k] * W1[k * 64 + j];
    float val = fmaxf(acc, 0.f) * W2[j];
#pragma unroll
    for (int off = 32; off > 0; off >>= 1)
        val += __shfl_down(val, off);
    if (j == 0) out[g] = val + b2[0];
}

// ------------------------------------------------------------------
extern "C" void kernel_launch(void* const* d_in, const int* in_sizes, int n_in,
                              void* d_out, int out_size, void* d_ws, size_t ws_size,
                              hipStream_t stream) {
    const float* h_in    = (const float*)d_in[0];
    const int*   ei      = (const int*)d_in[1];
    const int*   batch   = (const int*)d_in[2];
    const float* W_embed = (const float*)d_in[3];
    const float* b_embed = (const float*)d_in[4];
    const float* Wg      = (const float*)d_in[5];
    const float* bg      = (const float*)d_in[6];
    const float* Ws      = (const float*)d_in[7];
    const float* bs      = (const float*)d_in[8];
    const float* Wr      = (const float*)d_in[9];
    const float* br      = (const float*)d_in[10];
    const float* W1      = (const float*)d_in[11];
    const float* b1      = (const float*)d_in[12];
    const float* W2      = (const float*)d_in[13];
    const float* b2      = (const float*)d_in[14];
    float* out = (float*)d_out;

    float* ws   = (float*)d_ws;
    float* h    = ws;                                  // N*128
    float* big  = h + (size_t)N_NODES * 128;           // N*512
    float* wcat = big + (size_t)N_NODES * 512;         // 4*128*512
    float* bcat = wcat + NLAYERS * 128 * 512;          // 4*512
    float* hagg = bcat + NLAYERS * 512;                // 256*128

    build_wcat<<<(NLAYERS * 128 * 512 + 255) / 256, 256, 0, stream>>>(
        Wg, Ws, Wr, bg, bs, br, wcat, bcat);

    // embed: h = h_in @ W_embed + b_embed
    {
        dim3 grid((N_NODES + 63) / 64, 128 / 64);
        gemm_k128<<<grid, 256, 0, stream>>>(h_in, W_embed, b_embed, h, N_NODES, 128);
    }

    for (int l = 0; l < NLAYERS; l++) {
        dim3 grid((N_NODES + 63) / 64, 512 / 64);
        gemm_k128<<<grid, 256, 0, stream>>>(h, wcat + (size_t)l * 128 * 512,
                                            bcat + l * 512, big, N_NODES, 512);
        edge_kernel<<<(N_EDGES * 32 + 255) / 256, 256, 0, stream>>>(ei, big);
        update_kernel<<<(N_NODES * 32 + 255) / 256, 256, 0, stream>>>(h, big);
    }

    hipMemsetAsync(hagg, 0, (size_t)NGRAPH * 128 * sizeof(float), stream);
    pool_kernel<<<(N_NODES * 32 + 255) / 256, 256, 0, stream>>>(h, batch, hagg);
    head_kernel<<<NGRAPH, 64, 0, stream>>>(hagg, W1, b1, W2, b2, out);
}

// Round 2
// 1018.860 us; speedup vs baseline: 4.6825x; 4.6825x over previous
//
#include <hip/hip_runtime.h>
#include <hip/hip_bf16.h>
#include <math.h>

#define N_NODES 50000
#define N_EDGES 600000
#define HDIM    128
#define NLAYERS 4
#define NGRAPH  256

// ------------------------------------------------------------------
// GEMM: C[M x NC] = A[M x 128] @ B[128 x NC] + bias[NC]
// BM=64, BN=64, BK=32, 256 threads, 4x4 micro-tile per thread.
// ------------------------------------------------------------------
__global__ __launch_bounds__(256) void gemm_k128(
    const float* __restrict__ A, const float* __restrict__ B,
    const float* __restrict__ bias, float* __restrict__ C,
    int M, int NC)
{
    __shared__ float As[32][65];
    __shared__ float Bs[32][64];

    const int tid = threadIdx.x;
    const int tx = tid & 15, ty = tid >> 4;
    const int row0 = blockIdx.x * 64;
    const int col0 = blockIdx.y * 64;

    float acc[4][4];
#pragma unroll
    for (int i = 0; i < 4; i++)
#pragma unroll
        for (int j = 0; j < 4; j++) acc[i][j] = 0.f;

    for (int k0 = 0; k0 < 128; k0 += 32) {
#pragma unroll
        for (int u = 0; u < 2; u++) {
            int idx = tid + u * 256;
            int m   = idx >> 3;
            int k4  = (idx & 7) << 2;
            int row = row0 + m;
            if (row >= M) row = M - 1;
            const float4 av = *(const float4*)(A + (size_t)row * 128 + k0 + k4);
            As[k4 + 0][m] = av.x;
            As[k4 + 1][m] = av.y;
            As[k4 + 2][m] = av.z;
            As[k4 + 3][m] = av.w;
        }
#pragma unroll
        for (int u = 0; u < 2; u++) {
            int idx = tid + u * 256;
            int k   = idx >> 4;
            int n4  = (idx & 15) << 2;
            const float4 bv = *(const float4*)(B + (size_t)(k0 + k) * NC + col0 + n4);
            *(float4*)&Bs[k][n4] = bv;
        }
        __syncthreads();
#pragma unroll
        for (int k = 0; k < 32; k++) {
            float a0 = As[k][ty * 4 + 0];
            float a1 = As[k][ty * 4 + 1];
            float a2 = As[k][ty * 4 + 2];
            float a3 = As[k][ty * 4 + 3];
            float b0 = Bs[k][tx * 4 + 0];
            float b1 = Bs[k][tx * 4 + 1];
            float b2 = Bs[k][tx * 4 + 2];
            float b3 = Bs[k][tx * 4 + 3];
            acc[0][0] += a0 * b0; acc[0][1] += a0 * b1; acc[0][2] += a0 * b2; acc[0][3] += a0 * b3;
            acc[1][0] += a1 * b0; acc[1][1] += a1 * b1; acc[1][2] += a1 * b2; acc[1][3] += a1 * b3;
            acc[2][0] += a2 * b0; acc[2][1] += a2 * b1; acc[2][2] += a2 * b2; acc[2][3] += a2 * b3;
            acc[3][0] += a3 * b0; acc[3][1] += a3 * b1; acc[3][2] += a3 * b2; acc[3][3] += a3 * b3;
        }
        __syncthreads();
    }

#pragma unroll
    for (int i = 0; i < 4; i++) {
        int row = row0 + ty * 4 + i;
        if (row < M) {
            int col = col0 + tx * 4;
            float4 bv = *(const float4*)(bias + col);
            float4 cv;
            cv.x = acc[i][0] + bv.x;
            cv.y = acc[i][1] + bv.y;
            cv.z = acc[i][2] + bv.z;
            cv.w = acc[i][3] + bv.w;
            *(float4*)(C + (size_t)row * NC + col) = cv;
        }
    }
}

// ------------------------------------------------------------------
// Wcat[l] [128 x 512]: cols 0-127 Wg_top (bias bg) | 128-255 Wg_bot (bias 0)
//                    | 256-383 Ws (bias bs)        | 384-511 Wr (bias br)
// ------------------------------------------------------------------
__global__ void build_wcat(const float* __restrict__ Wg, const float* __restrict__ Ws,
                           const float* __restrict__ Wr, const float* __restrict__ bg,
                           const float* __restrict__ bs, const float* __restrict__ br,
                           float* __restrict__ wcat, float* __restrict__ bcat)
{
    int t = blockIdx.x * blockDim.x + threadIdx.x;
    if (t >= NLAYERS * 128 * 512) return;
    int l = t >> 16;
    int r = t & 65535;
    int k = r >> 9;
    int c = r & 511;
    float v;
    if (c < 128)      v = Wg[l * 32768 + k * 128 + c];
    else if (c < 256) v = Wg[l * 32768 + (128 + k) * 128 + (c - 128)];
    else if (c < 384) v = Ws[l * 16384 + k * 128 + (c - 256)];
    else              v = Wr[l * 16384 + k * 128 + (c - 384)];
    wcat[t] = v;
    if (k == 0) {
        float b;
        if (c < 128)      b = bg[l * 128 + c];
        else if (c < 256) b = 0.f;
        else if (c < 384) b = bs[l * 128 + (c - 256)];
        else              b = br[l * 128 + (c - 384)];
        bcat[l * 512 + c] = b;
    }
}

// ------------------------------------------------------------------
// CSR build (by receiver): histogram -> exclusive scan -> scatter
// ------------------------------------------------------------------
__global__ __launch_bounds__(256) void hist_kernel(const int* __restrict__ ei,
                                                   int* __restrict__ cnt)
{
    int e = blockIdx.x * blockDim.x + threadIdx.x;
    if (e < N_EDGES) atomicAdd(&cnt[ei[N_EDGES + e]], 1);
}

__global__ __launch_bounds__(1024) void scan_kernel(const int* __restrict__ cnt,
                                                    int* __restrict__ off)
{
    __shared__ int wsum[16];
    __shared__ int s_running;
    int tid = threadIdx.x;
    int lane = tid & 63, wid = tid >> 6;
    if (tid == 0) { s_running = 0; off[0] = 0; }
    __syncthreads();
    for (int base = 0; base < N_NODES; base += 4096) {
        int i0 = base + tid * 4;
        int v[4];
#pragma unroll
        for (int u = 0; u < 4; u++) v[u] = (i0 + u < N_NODES) ? cnt[i0 + u] : 0;
        int tsum = v[0] + v[1] + v[2] + v[3];
        // wave inclusive scan
        int x = tsum;
#pragma unroll
        for (int ofs = 1; ofs < 64; ofs <<= 1) {
            int y = __shfl_up(x, ofs);
            if (lane >= ofs) x += y;
        }
        if (lane == 63) wsum[wid] = x;
        __syncthreads();
        if (wid == 0) {
            int w = (lane < 16) ? wsum[lane] : 0;
#pragma unroll
            for (int ofs = 1; ofs < 16; ofs <<= 1) {
                int y = __shfl_up(w, ofs);
                if (lane >= ofs) w += y;
            }
            if (lane < 16) wsum[lane] = w;
        }
        __syncthreads();
        int wbase = (wid > 0) ? wsum[wid - 1] : 0;
        int excl = s_running + wbase + x - tsum;
        int run_total = s_running + wsum[15];
        __syncthreads();
#pragma unroll
        for (int u = 0; u < 4; u++) {
            excl += v[u];
            if (i0 + u < N_NODES) off[i0 + u + 1] = excl;
        }
        if (tid == 0) s_running = run_total;
        __syncthreads();
    }
}

__global__ __launch_bounds__(256) void scatter_kernel(const int* __restrict__ ei,
                                                      const int* __restrict__ off,
                                                      int* __restrict__ cur,
                                                      int* __restrict__ csr_send)
{
    int e = blockIdx.x * blockDim.x + threadIdx.x;
    if (e >= N_EDGES) return;
    int rec = ei[N_EDGES + e];
    int pos = off[rec] + atomicAdd(&cur[rec], 1);
    csr_send[pos] = ei[e];
}

// ------------------------------------------------------------------
// Node-centric aggregation + fused residual update.
// One 128-thread block per node n; thread j owns column j.
//   acc = r[n][j] (pre-seeded in big cols 384..512)
//   for each incoming edge (send s): acc += sigmoid(gr[n][j]+gs[s][j]) * sv[s][j]
//   h[n][j] += relu(acc)
// ------------------------------------------------------------------
__global__ __launch_bounds__(128) void agg_kernel(
    const int* __restrict__ off, const int* __restrict__ csr_send,
    const float* __restrict__ big, float* __restrict__ h)
{
    int n = blockIdx.x;
    int j = threadIdx.x;
    int p  = off[n];
    int p1 = off[n + 1];
    float gr  = big[(size_t)n * 512 + j];
    float acc = big[(size_t)n * 512 + 384 + j];
    for (; p + 1 < p1; p += 2) {
        int sa = csr_send[p];
        int sb = csr_send[p + 1];
        float gsa = big[(size_t)sa * 512 + 128 + j];
        float sva = big[(size_t)sa * 512 + 256 + j];
        float gsb = big[(size_t)sb * 512 + 128 + j];
        float svb = big[(size_t)sb * 512 + 256 + j];
        acc += sva / (1.f + __expf(-(gr + gsa)));
        acc += svb / (1.f + __expf(-(gr + gsb)));
    }
    if (p < p1) {
        int sa = csr_send[p];
        float gsa = big[(size_t)sa * 512 + 128 + j];
        float sva = big[(size_t)sa * 512 + 256 + j];
        acc += sva / (1.f + __expf(-(gr + gsa)));
    }
    h[(size_t)n * 128 + j] += fmaxf(acc, 0.f);
}

// ------------------------------------------------------------------
// Pool: batch is sorted, so each graph is a contiguous node range.
// One 128-thread block per graph; binary-search the range, reduce.
// ------------------------------------------------------------------
__global__ __launch_bounds__(128) void pool_kernel(
    const float* __restrict__ h, const int* __restrict__ batch,
    float* __restrict__ hagg)
{
    int g = blockIdx.x;
    __shared__ int s_lo, s_hi;
    if (threadIdx.x == 0) {
        int lo = 0, hi = N_NODES;
        while (lo < hi) { int mid = (lo + hi) >> 1; if (batch[mid] < g) lo = mid + 1; else hi = mid; }
        s_lo = lo;
        hi = N_NODES;
        while (lo < hi) { int mid = (lo + hi) >> 1; if (batch[mid] < g + 1) lo = mid + 1; else hi = mid; }
        s_hi = lo;
    }
    __syncthreads();
    float acc = 0.f;
    for (int n = s_lo; n < s_hi; n++)
        acc += h[(size_t)n * 128 + threadIdx.x];
    hagg[(size_t)g * 128 + threadIdx.x] = acc;
}

// ------------------------------------------------------------------
// Head: out[g] = relu(hagg[g] @ W1 + b1) @ W2 + b2
// ------------------------------------------------------------------
__global__ __launch_bounds__(64) void head_kernel(
    const float* __restrict__ hagg, const float* __restrict__ W1,
    const float* __restrict__ b1, const float* __restrict__ W2,
    const float* __restrict__ b2, float* __restrict__ out)
{
    int g = blockIdx.x;
    int j = threadIdx.x;
    float acc = b1[j];
    for (int k = 0; k < 128; k++)
        acc += hagg[(size_t)g * 128 + k] * W1[k * 64 + j];
    float val = fmaxf(acc, 0.f) * W2[j];
#pragma unroll
    for (int off = 32; off > 0; off >>= 1)
        val += __shfl_down(val, off);
    if (j == 0) out[g] = val + b2[0];
}

// ------------------------------------------------------------------
extern "C" void kernel_launch(void* const* d_in, const int* in_sizes, int n_in,
                              void* d_out, int out_size, void* d_ws, size_t ws_size,
                              hipStream_t stream) {
    const float* h_in    = (const float*)d_in[0];
    const int*   ei      = (const int*)d_in[1];
    const int*   batch   = (const int*)d_in[2];
    const float* W_embed = (const float*)d_in[3];
    const float* b_embed = (const float*)d_in[4];
    const float* Wg      = (const float*)d_in[5];
    const float* bg      = (const float*)d_in[6];
    const float* Ws      = (const float*)d_in[7];
    const float* bs      = (const float*)d_in[8];
    const float* Wr      = (const float*)d_in[9];
    const float* br      = (const float*)d_in[10];
    const float* W1      = (const float*)d_in[11];
    const float* b1      = (const float*)d_in[12];
    const float* W2      = (const float*)d_in[13];
    const float* b2      = (const float*)d_in[14];
    float* out = (float*)d_out;

    float* ws   = (float*)d_ws;
    float* h    = ws;                                   // N*128
    float* big  = h + (size_t)N_NODES * 128;            // N*512
    float* wcat = big + (size_t)N_NODES * 512;          // 4*128*512
    float* bcat = wcat + NLAYERS * 128 * 512;           // 4*512
    float* hagg = bcat + NLAYERS * 512;                 // 256*128
    int* cnt      = (int*)(hagg + NGRAPH * 128);        // N
    int* cur      = cnt + N_NODES;                      // N
    int* off      = cur + N_NODES;                      // N+1
    int* csr_send = off + N_NODES + 1;                  // E

    // CSR build (once per call; cnt+cur are contiguous -> one memset)
    hipMemsetAsync(cnt, 0, (size_t)2 * N_NODES * sizeof(int), stream);
    hist_kernel<<<(N_EDGES + 255) / 256, 256, 0, stream>>>(ei, cnt);
    scan_kernel<<<1, 1024, 0, stream>>>(cnt, off);
    scatter_kernel<<<(N_EDGES + 255) / 256, 256, 0, stream>>>(ei, off, cur, csr_send);

    build_wcat<<<(NLAYERS * 128 * 512 + 255) / 256, 256, 0, stream>>>(
        Wg, Ws, Wr, bg, bs, br, wcat, bcat);

    // embed: h = h_in @ W_embed + b_embed
    {
        dim3 grid((N_NODES + 63) / 64, 128 / 64);
        gemm_k128<<<grid, 256, 0, stream>>>(h_in, W_embed, b_embed, h, N_NODES, 128);
    }

    for (int l = 0; l < NLAYERS; l++) {
        dim3 grid((N_NODES + 63) / 64, 512 / 64);
        gemm_k128<<<grid, 256, 0, stream>>>(h, wcat + (size_t)l * 128 * 512,
                                            bcat + l * 512, big, N_NODES, 512);
        agg_kernel<<<N_NODES, 128, 0, stream>>>(off, csr_send, big, h);
    }

    pool_kernel<<<NGRAPH, 128, 0, stream>>>(h, batch, hagg);
    head_kernel<<<NGRAPH, 64, 0, stream>>>(hagg, W1, b1, W2, b2, out);
}

// Round 3
// 804.308 us; speedup vs baseline: 5.9316x; 1.2668x over previous
//
#include <hip/hip_runtime.h>
#include <hip/hip_bf16.h>
#include <math.h>

#define N_NODES 50000
#define N_EDGES 600000
#define HDIM    128
#define NLAYERS 4
#define NGRAPH  256

typedef __attribute__((ext_vector_type(8))) short short8;   // 8 x bf16 (4 VGPRs)
typedef __attribute__((ext_vector_type(4))) float float4v;  // MFMA acc
typedef unsigned short ushort_t;
typedef unsigned int uint_t;

__device__ __forceinline__ float bf2f(ushort_t u) {
    union { uint_t i; float f; } x; x.i = ((uint_t)u) << 16; return x.f;
}
__device__ __forceinline__ ushort_t f2bf(float f) {
    union { float f; uint_t i; } x; x.f = f;
    uint_t r = x.i + 0x7fff + ((x.i >> 16) & 1);   // RNE
    return (ushort_t)(r >> 16);
}

// ------------------------------------------------------------------
// MFMA GEMM: C[M x NC] = A_bf[M x 128] @ B + bias
// Bt is [NC x 128] bf16 (row n = column n of B, k-contiguous).
// No LDS: a lane's A-frag (A[m=lane&15][k=quad*8..+7]) is a contiguous
// 16B global read; a wave covers 16 rows x 64B = 16 full lines.
// Block = 4 waves; wave w does rows m0+16w..+15, cols n0..n0+127.
// Writes Cbf (bf16) always; Cf (fp32) if non-null.
// ------------------------------------------------------------------
__global__ __launch_bounds__(256) void mfma_gemm(
    const ushort_t* __restrict__ A, const ushort_t* __restrict__ Bt,
    const float* __restrict__ bias, ushort_t* __restrict__ Cbf,
    float* __restrict__ Cf, int M, int NC)
{
    const int tid  = threadIdx.x;
    const int wave = tid >> 6, lane = tid & 63;
    const int quad = lane >> 4, l16 = lane & 15;
    const int m0 = blockIdx.x * 64 + wave * 16;
    const int n0 = blockIdx.y * 128;

    int arow = m0 + l16;
    if (arow >= M) arow = M - 1;                 // clamp; stores guarded
    const ushort_t* aptr = A + (size_t)arow * 128 + quad * 8;

    float4v acc[8];
    float4v z = {0.f, 0.f, 0.f, 0.f};
#pragma unroll
    for (int i = 0; i < 8; i++) acc[i] = z;

#pragma unroll
    for (int k0 = 0; k0 < 128; k0 += 32) {
        short8 a = *(const short8*)(aptr + k0);
#pragma unroll
        for (int ni = 0; ni < 8; ni++) {
            const ushort_t* bptr = Bt + (size_t)(n0 + ni * 16 + l16) * 128 + k0 + quad * 8;
            short8 b = *(const short8*)bptr;
            acc[ni] = __builtin_amdgcn_mfma_f32_16x16x32_bf16(a, b, acc[ni], 0, 0, 0);
        }
    }

#pragma unroll
    for (int ni = 0; ni < 8; ni++) {
        int col = n0 + ni * 16 + l16;
        float bv = bias[col];
#pragma unroll
        for (int r = 0; r < 4; r++) {
            int row = m0 + quad * 4 + r;          // C/D: col=lane&15, row=quad*4+reg
            if (row < M) {
                float v = acc[ni][r] + bv;
                Cbf[(size_t)row * NC + col] = f2bf(v);
                if (Cf) Cf[(size_t)row * NC + col] = v;
            }
        }
    }
}

// ------------------------------------------------------------------
// Build transposed bf16 weight panels.
// wembed_t[n][k] = W_embed[k][n]
// ------------------------------------------------------------------
__global__ void build_wembed(const float* __restrict__ W, ushort_t* __restrict__ Wt)
{
    int t = blockIdx.x * blockDim.x + threadIdx.x;   // t = n*128 + k
    if (t >= 128 * 128) return;
    int n = t >> 7, k = t & 127;
    Wt[t] = f2bf(W[k * 128 + n]);
}

// wcat_t[l][p][k], physical column p of big:
//   p in [0,128)    : gr  = Wg[l][k][p]          bias bg[l][p]
//   p in [128,384)  : j=(p-128)>>1
//       p even      : gs  = Wg[l][128+k][j]      bias 0
//       p odd       : sv  = Ws[l][k][j]          bias bs[l][j]
//   p in [384,512)  : r   = Wr[l][k][p-384]      bias br[l][p-384]
__global__ void build_wcat(const float* __restrict__ Wg, const float* __restrict__ Ws,
                           const float* __restrict__ Wr, const float* __restrict__ bg,
                           const float* __restrict__ bs, const float* __restrict__ br,
                           ushort_t* __restrict__ wcat_t, float* __restrict__ bcat)
{
    int t = blockIdx.x * blockDim.x + threadIdx.x;   // t = ((l*512)+p)*128 + k
    if (t >= NLAYERS * 512 * 128) return;
    int l = t >> 16;
    int r = t & 65535;
    int p = r >> 7;
    int k = r & 127;
    float v, b;
    if (p < 128)      { v = Wg[l * 32768 + k * 128 + p];            b = bg[l * 128 + p]; }
    else if (p < 384) {
        int j = (p - 128) >> 1;
        if (((p - 128) & 1) == 0) { v = Wg[l * 32768 + (128 + k) * 128 + j]; b = 0.f; }
        else                      { v = Ws[l * 16384 + k * 128 + j];         b = bs[l * 128 + j]; }
    }
    else              { v = Wr[l * 16384 + k * 128 + (p - 384)];    b = br[l * 128 + (p - 384)]; }
    wcat_t[t] = f2bf(v);
    if (k == 0) bcat[l * 512 + p] = b;
}

__global__ __launch_bounds__(256) void cast_kernel(const float* __restrict__ src,
                                                   ushort_t* __restrict__ dst, int n)
{
    int t = blockIdx.x * blockDim.x + threadIdx.x;
    if (t < n) dst[t] = f2bf(src[t]);
}

// ------------------------------------------------------------------
// CSR build (by receiver): histogram -> exclusive scan -> scatter
// ------------------------------------------------------------------
__global__ __launch_bounds__(256) void hist_kernel(const int* __restrict__ ei,
                                                   int* __restrict__ cnt)
{
    int e = blockIdx.x * blockDim.x + threadIdx.x;
    if (e < N_EDGES) atomicAdd(&cnt[ei[N_EDGES + e]], 1);
}

__global__ __launch_bounds__(1024) void scan_kernel(const int* __restrict__ cnt,
                                                    int* __restrict__ off)
{
    __shared__ int wsum[16];
    __shared__ int s_running;
    int tid = threadIdx.x;
    int lane = tid & 63, wid = tid >> 6;
    if (tid == 0) { s_running = 0; off[0] = 0; }
    __syncthreads();
    for (int base = 0; base < N_NODES; base += 4096) {
        int i0 = base + tid * 4;
        int v[4];
#pragma unroll
        for (int u = 0; u < 4; u++) v[u] = (i0 + u < N_NODES) ? cnt[i0 + u] : 0;
        int tsum = v[0] + v[1] + v[2] + v[3];
        int x = tsum;
#pragma unroll
        for (int ofs = 1; ofs < 64; ofs <<= 1) {
            int y = __shfl_up(x, ofs);
            if (lane >= ofs) x += y;
        }
        if (lane == 63) wsum[wid] = x;
        __syncthreads();
        if (wid == 0) {
            int w = (lane < 16) ? wsum[lane] : 0;
#pragma unroll
            for (int ofs = 1; ofs < 16; ofs <<= 1) {
                int y = __shfl_up(w, ofs);
                if (lane >= ofs) w += y;
            }
            if (lane < 16) wsum[lane] = w;
        }
        __syncthreads();
        int wbase = (wid > 0) ? wsum[wid - 1] : 0;
        int excl = s_running + wbase + x - tsum;
        int run_total = s_running + wsum[15];
        __syncthreads();
#pragma unroll
        for (int u = 0; u < 4; u++) {
            excl += v[u];
            if (i0 + u < N_NODES) off[i0 + u + 1] = excl;
        }
        if (tid == 0) s_running = run_total;
        __syncthreads();
    }
}

__global__ __launch_bounds__(256) void scatter_kernel(const int* __restrict__ ei,
                                                      const int* __restrict__ off,
                                                      int* __restrict__ cur,
                                                      int* __restrict__ csr_send)
{
    int e = blockIdx.x * blockDim.x + threadIdx.x;
    if (e >= N_EDGES) return;
    int rec = ei[N_EDGES + e];
    int pos = off[rec] + atomicAdd(&cur[rec], 1);
    csr_send[pos] = ei[e];
}

// ------------------------------------------------------------------
// Node-centric aggregation + fused residual update (bf16 big).
// big cols: [0,128) gr | [128,384) interleaved (gs,sv) pairs | [384,512) r
// Thread j: one uint load per edge = packed (gs[j], sv[j]).
// ------------------------------------------------------------------
__global__ __launch_bounds__(128) void agg_kernel(
    const int* __restrict__ off, const int* __restrict__ csr_send,
    const ushort_t* __restrict__ big, float* __restrict__ h,
    ushort_t* __restrict__ h_bf)
{
    int n = blockIdx.x;
    int j = threadIdx.x;
    int p  = off[n];
    int p1 = off[n + 1];
    float gr  = bf2f(big[(size_t)n * 512 + j]);
    float acc = bf2f(big[(size_t)n * 512 + 384 + j]);
    for (; p + 1 < p1; p += 2) {
        int sa = csr_send[p];
        int sb = csr_send[p + 1];
        uint_t pa = *(const uint_t*)(big + (size_t)sa * 512 + 128 + 2 * j);
        uint_t pb = *(const uint_t*)(big + (size_t)sb * 512 + 128 + 2 * j);
        float gsa = bf2f((ushort_t)(pa & 0xffff)), sva = bf2f((ushort_t)(pa >> 16));
        float gsb = bf2f((ushort_t)(pb & 0xffff)), svb = bf2f((ushort_t)(pb >> 16));
        acc += sva / (1.f + __expf(-(gr + gsa)));
        acc += svb / (1.f + __expf(-(gr + gsb)));
    }
    if (p < p1) {
        int sa = csr_send[p];
        uint_t pa = *(const uint_t*)(big + (size_t)sa * 512 + 128 + 2 * j);
        float gsa = bf2f((ushort_t)(pa & 0xffff)), sva = bf2f((ushort_t)(pa >> 16));
        acc += sva / (1.f + __expf(-(gr + gsa)));
    }
    float hn = h[(size_t)n * 128 + j] + fmaxf(acc, 0.f);
    h[(size_t)n * 128 + j] = hn;
    h_bf[(size_t)n * 128 + j] = f2bf(hn);
}

// ------------------------------------------------------------------
// Pool: batch sorted -> contiguous range per graph.
// ------------------------------------------------------------------
__global__ __launch_bounds__(128) void pool_kernel(
    const float* __restrict__ h, const int* __restrict__ batch,
    float* __restrict__ hagg)
{
    int g = blockIdx.x;
    __shared__ int s_lo, s_hi;
    if (threadIdx.x == 0) {
        int lo = 0, hi = N_NODES;
        while (lo < hi) { int mid = (lo + hi) >> 1; if (batch[mid] < g) lo = mid + 1; else hi = mid; }
        s_lo = lo;
        hi = N_NODES;
        while (lo < hi) { int mid = (lo + hi) >> 1; if (batch[mid] < g + 1) lo = mid + 1; else hi = mid; }
        s_hi = lo;
    }
    __syncthreads();
    float acc = 0.f;
    for (int n = s_lo; n < s_hi; n++)
        acc += h[(size_t)n * 128 + threadIdx.x];
    hagg[(size_t)g * 128 + threadIdx.x] = acc;
}

// ------------------------------------------------------------------
// Head: out[g] = relu(hagg[g] @ W1 + b1) @ W2 + b2
// ------------------------------------------------------------------
__global__ __launch_bounds__(64) void head_kernel(
    const float* __restrict__ hagg, const float* __restrict__ W1,
    const float* __restrict__ b1, const float* __restrict__ W2,
    const float* __restrict__ b2, float* __restrict__ out)
{
    int g = blockIdx.x;
    int j = threadIdx.x;
    float acc = b1[j];
    for (int k = 0; k < 128; k++)
        acc += hagg[(size_t)g * 128 + k] * W1[k * 64 + j];
    float val = fmaxf(acc, 0.f) * W2[j];
#pragma unroll
    for (int off = 32; off > 0; off >>= 1)
        val += __shfl_down(val, off);
    if (j == 0) out[g] = val + b2[0];
}

// ------------------------------------------------------------------
extern "C" void kernel_launch(void* const* d_in, const int* in_sizes, int n_in,
                              void* d_out, int out_size, void* d_ws, size_t ws_size,
                              hipStream_t stream) {
    const float* h_in    = (const float*)d_in[0];
    const int*   ei      = (const int*)d_in[1];
    const int*   batch   = (const int*)d_in[2];
    const float* W_embed = (const float*)d_in[3];
    const float* b_embed = (const float*)d_in[4];
    const float* Wg      = (const float*)d_in[5];
    const float* bg      = (const float*)d_in[6];
    const float* Ws      = (const float*)d_in[7];
    const float* bs      = (const float*)d_in[8];
    const float* Wr      = (const float*)d_in[9];
    const float* br      = (const float*)d_in[10];
    const float* W1      = (const float*)d_in[11];
    const float* b1      = (const float*)d_in[12];
    const float* W2      = (const float*)d_in[13];
    const float* b2      = (const float*)d_in[14];
    float* out = (float*)d_out;

    // workspace layout (fp32 first, then bf16 — all 16B-aligned)
    float* ws   = (float*)d_ws;
    float*    h        = ws;                                  // N*128 f32
    float*    hagg     = h + (size_t)N_NODES * 128;           // 256*128
    float*    bcat     = hagg + NGRAPH * 128;                 // 4*512
    ushort_t* a_bf     = (ushort_t*)(bcat + NLAYERS * 512);   // N*128 bf16
    ushort_t* h_bf     = a_bf + (size_t)N_NODES * 128;        // N*128 bf16
    ushort_t* big      = h_bf + (size_t)N_NODES * 128;        // N*512 bf16
    ushort_t* wembed_t = big + (size_t)N_NODES * 512;         // 128*128 bf16
    ushort_t* wcat_t   = wembed_t + 128 * 128;                // 4*512*128 bf16
    int* cnt      = (int*)(wcat_t + NLAYERS * 512 * 128);     // N
    int* cur      = cnt + N_NODES;                            // N
    int* off      = cur + N_NODES;                            // N+1
    int* csr_send = off + N_NODES + 1;                        // E

    // CSR build
    hipMemsetAsync(cnt, 0, (size_t)2 * N_NODES * sizeof(int), stream);
    hist_kernel<<<(N_EDGES + 255) / 256, 256, 0, stream>>>(ei, cnt);
    scan_kernel<<<1, 1024, 0, stream>>>(cnt, off);
    scatter_kernel<<<(N_EDGES + 255) / 256, 256, 0, stream>>>(ei, off, cur, csr_send);

    // weight panels
    build_wembed<<<(128 * 128 + 255) / 256, 256, 0, stream>>>(W_embed, wembed_t);
    build_wcat<<<(NLAYERS * 512 * 128 + 255) / 256, 256, 0, stream>>>(
        Wg, Ws, Wr, bg, bs, br, wcat_t, bcat);

    // embed: h = h_in @ W_embed + b_embed (fp32 + bf16 shadow)
    cast_kernel<<<((N_NODES * 128) + 255) / 256, 256, 0, stream>>>(h_in, a_bf, N_NODES * 128);
    {
        dim3 grid((N_NODES + 63) / 64, 1);
        mfma_gemm<<<grid, 256, 0, stream>>>(a_bf, wembed_t, b_embed, h_bf, h, N_NODES, 128);
    }

    for (int l = 0; l < NLAYERS; l++) {
        dim3 grid((N_NODES + 63) / 64, 4);
        mfma_gemm<<<grid, 256, 0, stream>>>(h_bf, wcat_t + (size_t)l * 512 * 128,
                                            bcat + l * 512, big, nullptr, N_NODES, 512);
        agg_kernel<<<N_NODES, 128, 0, stream>>>(off, csr_send, big, h, h_bf);
    }

    pool_kernel<<<NGRAPH, 128, 0, stream>>>(h, batch, hagg);
    head_kernel<<<NGRAPH, 64, 0, stream>>>(hagg, W1, b1, W2, b2, out);
}

// Round 4
// 748.365 us; speedup vs baseline: 6.3750x; 1.0748x over previous
//
#include <hip/hip_runtime.h>
#include <hip/hip_bf16.h>
#include <math.h>

#define N_NODES 50000
#define N_EDGES 600000
#define HDIM    128
#define NLAYERS 4
#define NGRAPH  256

typedef __attribute__((ext_vector_type(8))) short short8;   // 8 x bf16 (4 VGPRs)
typedef __attribute__((ext_vector_type(4))) float float4v;  // MFMA acc
typedef unsigned short ushort_t;
typedef unsigned int uint_t;

__device__ __forceinline__ float bf2f(ushort_t u) {
    union { uint_t i; float f; } x; x.i = ((uint_t)u) << 16; return x.f;
}
__device__ __forceinline__ ushort_t f2bf(float f) {
    union { float f; uint_t i; } x; x.f = f;
    uint_t r = x.i + 0x7fff + ((x.i >> 16) & 1);   // RNE
    return (ushort_t)(r >> 16);
}

// ------------------------------------------------------------------
// Split-bf16 MFMA GEMM, B-stationary in registers.
// C[M x NC] = (Ahi+Alo) @ (Bhi+Blo) + bias   (lo*lo dropped)
// B panels are [NC x 128] (row n = column n, k-contiguous).
// Block = 4 waves; wave owns 32 cols (2 ni), preloads 16 B-frags once,
// grid-strides over 16-row A tiles. No LDS.
// mode 0 (embed): write h (f32) + hhi/hlo (bf16)
// mode 1 (layer): col<128 -> grf f32 | 128..383 -> bigmid bf16 | >=384 -> ragg f32
// ------------------------------------------------------------------
__global__ __launch_bounds__(256) void mfma_gemm3(
    const ushort_t* __restrict__ Ahi, const ushort_t* __restrict__ Alo,
    const ushort_t* __restrict__ Bhi, const ushort_t* __restrict__ Blo,
    const float* __restrict__ bias, int M, int mode,
    float* __restrict__ hout, ushort_t* __restrict__ hhi, ushort_t* __restrict__ hlo,
    float* __restrict__ grf, ushort_t* __restrict__ bigmid, float* __restrict__ ragg)
{
    const int tid  = threadIdx.x;
    const int wave = tid >> 6, lane = tid & 63;
    const int quad = lane >> 4, l16 = lane & 15;
    const int colbase = blockIdx.y * 128 + wave * 32;   // wave covers 32 cols
    const int NC = (mode == 0) ? 128 : 512;

    // B fragments: resident for the whole kernel
    short8 bh[2][4], bl[2][4];
#pragma unroll
    for (int c = 0; c < 2; c++)
#pragma unroll
        for (int k0 = 0; k0 < 4; k0++) {
            size_t boff = (size_t)(colbase + c * 16 + l16) * 128 + k0 * 32 + quad * 8;
            bh[c][k0] = *(const short8*)(Bhi + boff);
            bl[c][k0] = *(const short8*)(Blo + boff);
        }

    const int ntiles = (M + 15) >> 4;
    for (int tile = blockIdx.x; tile < ntiles; tile += gridDim.x) {
        int arow = tile * 16 + l16;
        if (arow >= M) arow = M - 1;                    // clamp; stores guarded
        const ushort_t* ah = Ahi + (size_t)arow * 128 + quad * 8;
        const ushort_t* al = Alo + (size_t)arow * 128 + quad * 8;
        short8 a_hi[4], a_lo[4];
#pragma unroll
        for (int k0 = 0; k0 < 4; k0++) {
            a_hi[k0] = *(const short8*)(ah + k0 * 32);
            a_lo[k0] = *(const short8*)(al + k0 * 32);
        }
        float4v acc[2];
        float4v z = {0.f, 0.f, 0.f, 0.f};
        acc[0] = z; acc[1] = z;
#pragma unroll
        for (int k0 = 0; k0 < 4; k0++) {
#pragma unroll
            for (int c = 0; c < 2; c++) {
                acc[c] = __builtin_amdgcn_mfma_f32_16x16x32_bf16(a_hi[k0], bh[c][k0], acc[c], 0, 0, 0);
                acc[c] = __builtin_amdgcn_mfma_f32_16x16x32_bf16(a_lo[k0], bh[c][k0], acc[c], 0, 0, 0);
                acc[c] = __builtin_amdgcn_mfma_f32_16x16x32_bf16(a_hi[k0], bl[c][k0], acc[c], 0, 0, 0);
            }
        }
#pragma unroll
        for (int c = 0; c < 2; c++) {
            int col = colbase + c * 16 + l16;
            float bv = bias[col];
#pragma unroll
            for (int r = 0; r < 4; r++) {
                int row = tile * 16 + quad * 4 + r;     // C/D: col=lane&15, row=quad*4+reg
                if (row < M) {
                    float v = acc[c][r] + bv;
                    if (mode == 0) {
                        hout[(size_t)row * 128 + col] = v;
                        ushort_t hi = f2bf(v);
                        hhi[(size_t)row * 128 + col] = hi;
                        hlo[(size_t)row * 128 + col] = f2bf(v - bf2f(hi));
                    } else {
                        if (col < 128)      grf[(size_t)row * 128 + col] = v;
                        else if (col < 384) bigmid[(size_t)row * 256 + col - 128] = f2bf(v);
                        else                ragg[(size_t)row * 128 + col - 384] = v;
                    }
                }
            }
        }
    }
}

// ------------------------------------------------------------------
// Weight panels (transposed, split hi/lo).
// wembed_t[n][k] = W_embed[k][n]
// ------------------------------------------------------------------
__global__ void build_wembed(const float* __restrict__ W,
                             ushort_t* __restrict__ Whi, ushort_t* __restrict__ Wlo)
{
    int t = blockIdx.x * blockDim.x + threadIdx.x;   // t = n*128 + k
    if (t >= 128 * 128) return;
    int n = t >> 7, k = t & 127;
    float v = W[k * 128 + n];
    ushort_t hi = f2bf(v);
    Whi[t] = hi;
    Wlo[t] = f2bf(v - bf2f(hi));
}

// wcat_t[l][p][k], physical column p:
//   p in [0,128)   : gr = Wg[l][k][p]              bias bg[l][p]   -> grf
//   p in [128,384) : j=(p-128)>>1
//       even       : gs = Wg[l][128+k][j]          bias 0          -> bigmid
//       odd        : sv = Ws[l][k][j]              bias bs[l][j]   -> bigmid
//   p in [384,512) : r  = Wr[l][k][p-384]          bias br[l][p-384] -> ragg
__global__ void build_wcat(const float* __restrict__ Wg, const float* __restrict__ Ws,
                           const float* __restrict__ Wr, const float* __restrict__ bg,
                           const float* __restrict__ bs, const float* __restrict__ br,
                           ushort_t* __restrict__ Whi, ushort_t* __restrict__ Wlo,
                           float* __restrict__ bcat)
{
    int t = blockIdx.x * blockDim.x + threadIdx.x;   // t = ((l*512)+p)*128 + k
    if (t >= NLAYERS * 512 * 128) return;
    int l = t >> 16;
    int r = t & 65535;
    int p = r >> 7;
    int k = r & 127;
    float v, b;
    if (p < 128)      { v = Wg[l * 32768 + k * 128 + p];            b = bg[l * 128 + p]; }
    else if (p < 384) {
        int j = (p - 128) >> 1;
        if (((p - 128) & 1) == 0) { v = Wg[l * 32768 + (128 + k) * 128 + j]; b = 0.f; }
        else                      { v = Ws[l * 16384 + k * 128 + j];         b = bs[l * 128 + j]; }
    }
    else              { v = Wr[l * 16384 + k * 128 + (p - 384)];    b = br[l * 128 + (p - 384)]; }
    ushort_t hi = f2bf(v);
    Whi[t] = hi;
    Wlo[t] = f2bf(v - bf2f(hi));
    if (k == 0) bcat[l * 512 + p] = b;
}

__global__ __launch_bounds__(256) void cast_split(const float* __restrict__ src,
                                                  ushort_t* __restrict__ hi,
                                                  ushort_t* __restrict__ lo, int n)
{
    int t = blockIdx.x * blockDim.x + threadIdx.x;
    if (t >= n) return;
    float v = src[t];
    ushort_t h = f2bf(v);
    hi[t] = h;
    lo[t] = f2bf(v - bf2f(h));
}

// ------------------------------------------------------------------
// CSR build (by receiver): histogram -> exclusive scan -> scatter
// ------------------------------------------------------------------
__global__ __launch_bounds__(256) void hist_kernel(const int* __restrict__ ei,
                                                   int* __restrict__ cnt)
{
    int e = blockIdx.x * blockDim.x + threadIdx.x;
    if (e < N_EDGES) atomicAdd(&cnt[ei[N_EDGES + e]], 1);
}

__global__ __launch_bounds__(1024) void scan_kernel(const int* __restrict__ cnt,
                                                    int* __restrict__ off)
{
    __shared__ int wsum[16];
    __shared__ int s_running;
    int tid = threadIdx.x;
    int lane = tid & 63, wid = tid >> 6;
    if (tid == 0) { s_running = 0; off[0] = 0; }
    __syncthreads();
    for (int base = 0; base < N_NODES; base += 4096) {
        int i0 = base + tid * 4;
        int v[4];
#pragma unroll
        for (int u = 0; u < 4; u++) v[u] = (i0 + u < N_NODES) ? cnt[i0 + u] : 0;
        int tsum = v[0] + v[1] + v[2] + v[3];
        int x = tsum;
#pragma unroll
        for (int ofs = 1; ofs < 64; ofs <<= 1) {
            int y = __shfl_up(x, ofs);
            if (lane >= ofs) x += y;
        }
        if (lane == 63) wsum[wid] = x;
        __syncthreads();
        if (wid == 0) {
            int w = (lane < 16) ? wsum[lane] : 0;
#pragma unroll
            for (int ofs = 1; ofs < 16; ofs <<= 1) {
                int y = __shfl_up(w, ofs);
                if (lane >= ofs) w += y;
            }
            if (lane < 16) wsum[lane] = w;
        }
        __syncthreads();
        int wbase = (wid > 0) ? wsum[wid - 1] : 0;
        int excl = s_running + wbase + x - tsum;
        int run_total = s_running + wsum[15];
        __syncthreads();
#pragma unroll
        for (int u = 0; u < 4; u++) {
            excl += v[u];
            if (i0 + u < N_NODES) off[i0 + u + 1] = excl;
        }
        if (tid == 0) s_running = run_total;
        __syncthreads();
    }
}

__global__ __launch_bounds__(256) void scatter_kernel(const int* __restrict__ ei,
                                                      const int* __restrict__ off,
                                                      int* __restrict__ cur,
                                                      int* __restrict__ csr_send)
{
    int e = blockIdx.x * blockDim.x + threadIdx.x;
    if (e >= N_EDGES) return;
    int rec = ei[N_EDGES + e];
    int pos = off[rec] + atomicAdd(&cur[rec], 1);
    csr_send[pos] = ei[e];
}

// ------------------------------------------------------------------
// Node-centric aggregation + fused residual update.
// bigmid[n][2j] = gs[n][j], bigmid[n][2j+1] = sv[n][j]  (bf16)
// gr, r in fp32 side arrays. 4x unrolled edge loop.
// ------------------------------------------------------------------
__device__ __forceinline__ float gate_msg(uint_t pk, float gr) {
    float gs = bf2f((ushort_t)(pk & 0xffff));
    float sv = bf2f((ushort_t)(pk >> 16));
    return sv / (1.f + __expf(-(gr + gs)));
}

__global__ __launch_bounds__(128) void agg_kernel(
    const int* __restrict__ off, const int* __restrict__ csr_send,
    const ushort_t* __restrict__ bigmid, const float* __restrict__ grf,
    const float* __restrict__ ragg, float* __restrict__ h,
    ushort_t* __restrict__ hhi, ushort_t* __restrict__ hlo)
{
    int n = blockIdx.x;
    int j = threadIdx.x;
    int p  = off[n];
    int p1 = off[n + 1];
    float gr  = grf[(size_t)n * 128 + j];
    float acc = ragg[(size_t)n * 128 + j];
    for (; p + 3 < p1; p += 4) {
        int s0 = csr_send[p + 0];
        int s1 = csr_send[p + 1];
        int s2 = csr_send[p + 2];
        int s3 = csr_send[p + 3];
        uint_t q0 = *(const uint_t*)(bigmid + (size_t)s0 * 256 + 2 * j);
        uint_t q1 = *(const uint_t*)(bigmid + (size_t)s1 * 256 + 2 * j);
        uint_t q2 = *(const uint_t*)(bigmid + (size_t)s2 * 256 + 2 * j);
        uint_t q3 = *(const uint_t*)(bigmid + (size_t)s3 * 256 + 2 * j);
        acc += gate_msg(q0, gr);
        acc += gate_msg(q1, gr);
        acc += gate_msg(q2, gr);
        acc += gate_msg(q3, gr);
    }
    for (; p < p1; p++) {
        int s0 = csr_send[p];
        uint_t q0 = *(const uint_t*)(bigmid + (size_t)s0 * 256 + 2 * j);
        acc += gate_msg(q0, gr);
    }
    float hn = h[(size_t)n * 128 + j] + fmaxf(acc, 0.f);
    h[(size_t)n * 128 + j] = hn;
    ushort_t hi = f2bf(hn);
    hhi[(size_t)n * 128 + j] = hi;
    hlo[(size_t)n * 128 + j] = f2bf(hn - bf2f(hi));
}

// ------------------------------------------------------------------
// Pool: batch sorted -> contiguous range per graph.
// ------------------------------------------------------------------
__global__ __launch_bounds__(128) void pool_kernel(
    const float* __restrict__ h, const int* __restrict__ batch,
    float* __restrict__ hagg)
{
    int g = blockIdx.x;
    __shared__ int s_lo, s_hi;
    if (threadIdx.x == 0) {
        int lo = 0, hi = N_NODES;
        while (lo < hi) { int mid = (lo + hi) >> 1; if (batch[mid] < g) lo = mid + 1; else hi = mid; }
        s_lo = lo;
        hi = N_NODES;
        while (lo < hi) { int mid = (lo + hi) >> 1; if (batch[mid] < g + 1) lo = mid + 1; else hi = mid; }
        s_hi = lo;
    }
    __syncthreads();
    float acc = 0.f;
    for (int n = s_lo; n < s_hi; n++)
        acc += h[(size_t)n * 128 + threadIdx.x];
    hagg[(size_t)g * 128 + threadIdx.x] = acc;
}

// ------------------------------------------------------------------
// Head: out[g] = relu(hagg[g] @ W1 + b1) @ W2 + b2
// ------------------------------------------------------------------
__global__ __launch_bounds__(64) void head_kernel(
    const float* __restrict__ hagg, const float* __restrict__ W1,
    const float* __restrict__ b1, const float* __restrict__ W2,
    const float* __restrict__ b2, float* __restrict__ out)
{
    int g = blockIdx.x;
    int j = threadIdx.x;
    float acc = b1[j];
    for (int k = 0; k < 128; k++)
        acc += hagg[(size_t)g * 128 + k] * W1[k * 64 + j];
    float val = fmaxf(acc, 0.f) * W2[j];
#pragma unroll
    for (int off = 32; off > 0; off >>= 1)
        val += __shfl_down(val, off);
    if (j == 0) out[g] = val + b2[0];
}

// ------------------------------------------------------------------
extern "C" void kernel_launch(void* const* d_in, const int* in_sizes, int n_in,
                              void* d_out, int out_size, void* d_ws, size_t ws_size,
                              hipStream_t stream) {
    const float* h_in    = (const float*)d_in[0];
    const int*   ei      = (const int*)d_in[1];
    const int*   batch   = (const int*)d_in[2];
    const float* W_embed = (const float*)d_in[3];
    const float* b_embed = (const float*)d_in[4];
    const float* Wg      = (const float*)d_in[5];
    const float* bg      = (const float*)d_in[6];
    const float* Ws      = (const float*)d_in[7];
    const float* bs      = (const float*)d_in[8];
    const float* Wr      = (const float*)d_in[9];
    const float* br      = (const float*)d_in[10];
    const float* W1      = (const float*)d_in[11];
    const float* b1      = (const float*)d_in[12];
    const float* W2      = (const float*)d_in[13];
    const float* b2      = (const float*)d_in[14];
    float* out = (float*)d_out;

    // workspace layout (fp32 first, then bf16, then ints — 16B-aligned chunks)
    float* ws = (float*)d_ws;
    float*    h     = ws;                                    // N*128 f32
    float*    grf   = h + (size_t)N_NODES * 128;             // N*128 f32
    float*    ragg  = grf + (size_t)N_NODES * 128;           // N*128 f32
    float*    hagg  = ragg + (size_t)N_NODES * 128;          // G*128 f32
    float*    bcat  = hagg + NGRAPH * 128;                   // 4*512 f32
    ushort_t* ahi   = (ushort_t*)(bcat + NLAYERS * 512);     // N*128 bf16
    ushort_t* alo   = ahi + (size_t)N_NODES * 128;           // N*128
    ushort_t* hhi   = alo + (size_t)N_NODES * 128;           // N*128
    ushort_t* hlo   = hhi + (size_t)N_NODES * 128;           // N*128
    ushort_t* bigmid= hlo + (size_t)N_NODES * 128;           // N*256 bf16
    ushort_t* wehi  = bigmid + (size_t)N_NODES * 256;        // 128*128
    ushort_t* welo  = wehi + 128 * 128;                      // 128*128
    ushort_t* wchi  = welo + 128 * 128;                      // 4*512*128
    ushort_t* wclo  = wchi + NLAYERS * 512 * 128;            // 4*512*128
    int* cnt      = (int*)(wclo + NLAYERS * 512 * 128);      // N
    int* cur      = cnt + N_NODES;                           // N
    int* off      = cur + N_NODES;                           // N+1
    int* csr_send = off + N_NODES + 1;                       // E

    // CSR build
    hipMemsetAsync(cnt, 0, (size_t)2 * N_NODES * sizeof(int), stream);
    hist_kernel<<<(N_EDGES + 255) / 256, 256, 0, stream>>>(ei, cnt);
    scan_kernel<<<1, 1024, 0, stream>>>(cnt, off);
    scatter_kernel<<<(N_EDGES + 255) / 256, 256, 0, stream>>>(ei, off, cur, csr_send);

    // weight panels (hi/lo split)
    build_wembed<<<(128 * 128 + 255) / 256, 256, 0, stream>>>(W_embed, wehi, welo);
    build_wcat<<<(NLAYERS * 512 * 128 + 255) / 256, 256, 0, stream>>>(
        Wg, Ws, Wr, bg, bs, br, wchi, wclo, bcat);

    // embed: h = h_in @ W_embed + b_embed
    cast_split<<<((N_NODES * 128) + 255) / 256, 256, 0, stream>>>(h_in, ahi, alo, N_NODES * 128);
    {
        dim3 grid(1024, 1);
        mfma_gemm3<<<grid, 256, 0, stream>>>(ahi, alo, wehi, welo, b_embed,
                                             N_NODES, 0, h, hhi, hlo,
                                             nullptr, nullptr, nullptr);
    }

    for (int l = 0; l < NLAYERS; l++) {
        dim3 grid(256, 4);
        mfma_gemm3<<<grid, 256, 0, stream>>>(hhi, hlo,
                                             wchi + (size_t)l * 512 * 128,
                                             wclo + (size_t)l * 512 * 128,
                                             bcat + l * 512, N_NODES, 1,
                                             nullptr, nullptr, nullptr,
                                             grf, bigmid, ragg);
        agg_kernel<<<N_NODES, 128, 0, stream>>>(off, csr_send, bigmid, grf, ragg,
                                                h, hhi, hlo);
    }

    pool_kernel<<<NGRAPH, 128, 0, stream>>>(h, batch, hagg);
    head_kernel<<<NGRAPH, 64, 0, stream>>>(hagg, W1, b1, W2, b2, out);
}

// Round 5
// 574.555 us; speedup vs baseline: 8.3035x; 1.3025x over previous
//
#include <hip/hip_runtime.h>
#include <hip/hip_bf16.h>
#include <math.h>

#define N_NODES 50000
#define N_EDGES 600000
#define HDIM    128
#define NLAYERS 4
#define NGRAPH  256

typedef _Float16 half8 __attribute__((ext_vector_type(8)));   // 8 x fp16 (4 VGPRs)
typedef __attribute__((ext_vector_type(4))) float float4v;    // MFMA acc
typedef unsigned short ushort_t;
typedef unsigned int uint_t;

__device__ __forceinline__ float h2f(ushort_t u) {
    union { ushort_t u; _Float16 h; } x; x.u = u; return (float)x.h;
}
__device__ __forceinline__ ushort_t f2h(float f) {
    union { ushort_t u; _Float16 h; } x; x.h = (_Float16)f; return x.u;
}

// ------------------------------------------------------------------
// fp16 MFMA GEMM, B-stationary, A register-double-buffered. No LDS.
// C[M x NC] = A @ B + bias ; Bt is [NC x 128] fp16 (k-contiguous rows).
// Each wave owns 64 cols (4 frags), preloads 16 B-frags once, then
// grid-strides over 16-row A tiles with next-tile prefetch.
// mode 0 (embed, NC=128, 2 waves/block): write h f32 + h16 fp16
// mode 1 (layer, NC=512, 4 waves/block):
//   col<128 -> gr16 | 128..383 -> bigmid (gs,sv interleaved) | >=384 -> r16
// ------------------------------------------------------------------
__global__ __launch_bounds__(256) void mfma_gemm_f16(
    const ushort_t* __restrict__ A, const ushort_t* __restrict__ Bt,
    const float* __restrict__ bias, int M, int mode,
    float* __restrict__ hout, ushort_t* __restrict__ h16,
    ushort_t* __restrict__ gr16, ushort_t* __restrict__ bigmid,
    ushort_t* __restrict__ r16)
{
    const int tid  = threadIdx.x;
    const int wave = tid >> 6, lane = tid & 63;
    const int quad = lane >> 4, l16 = lane & 15;
    const int nwaves = blockDim.x >> 6;
    const int colbase = (blockIdx.y * nwaves + wave) * 64;   // 64 cols per wave

    // B fragments: resident for the whole kernel (16 x 16B loads)
    half8 bf[4][4];
#pragma unroll
    for (int c = 0; c < 4; c++)
#pragma unroll
        for (int k0 = 0; k0 < 4; k0++)
            bf[c][k0] = *(const half8*)(Bt + (size_t)(colbase + c * 16 + l16) * 128
                                           + k0 * 32 + quad * 8);

    const int ntiles = (M + 15) >> 4;
    int tile = blockIdx.x;
    if (tile >= ntiles) return;

    half8 acur[4], anext[4];
    {
        int arow = tile * 16 + l16;
        if (arow >= M) arow = M - 1;
        const ushort_t* ap = A + (size_t)arow * 128 + quad * 8;
#pragma unroll
        for (int k0 = 0; k0 < 4; k0++) acur[k0] = *(const half8*)(ap + k0 * 32);
    }

    while (true) {
        const int nt = tile + gridDim.x;
        const bool have_next = nt < ntiles;
        if (have_next) {
            int arow = nt * 16 + l16;
            if (arow >= M) arow = M - 1;
            const ushort_t* ap = A + (size_t)arow * 128 + quad * 8;
#pragma unroll
            for (int k0 = 0; k0 < 4; k0++) anext[k0] = *(const half8*)(ap + k0 * 32);
        }

        float4v acc[4];
        float4v z = {0.f, 0.f, 0.f, 0.f};
#pragma unroll
        for (int c = 0; c < 4; c++) acc[c] = z;
#pragma unroll
        for (int k0 = 0; k0 < 4; k0++)
#pragma unroll
            for (int c = 0; c < 4; c++)
                acc[c] = __builtin_amdgcn_mfma_f32_16x16x32_f16(acur[k0], bf[c][k0], acc[c], 0, 0, 0);

        // epilogue — C/D: col=lane&15, row=quad*4+reg
#pragma unroll
        for (int c = 0; c < 4; c++) {
            const int col = colbase + c * 16 + l16;
            const float bv = bias[col];
#pragma unroll
            for (int r = 0; r < 4; r++) {
                const int row = tile * 16 + quad * 4 + r;
                if (row < M) {
                    const float v = acc[c][r] + bv;
                    if (mode == 0) {
                        hout[(size_t)row * 128 + col] = v;
                        h16[(size_t)row * 128 + col] = f2h(v);
                    } else {
                        if (col < 128)      gr16[(size_t)row * 128 + col] = f2h(v);
                        else if (col < 384) bigmid[(size_t)row * 256 + col - 128] = f2h(v);
                        else                r16[(size_t)row * 128 + col - 384] = f2h(v);
                    }
                }
            }
        }

        if (!have_next) break;
#pragma unroll
        for (int k0 = 0; k0 < 4; k0++) acur[k0] = anext[k0];
        tile = nt;
    }
}

// ------------------------------------------------------------------
// Weight panels (transposed, fp16). wembed_t[n][k] = W_embed[k][n]
// ------------------------------------------------------------------
__global__ void build_wembed(const float* __restrict__ W, ushort_t* __restrict__ Wt)
{
    int t = blockIdx.x * blockDim.x + threadIdx.x;   // t = n*128 + k
    if (t >= 128 * 128) return;
    int n = t >> 7, k = t & 127;
    Wt[t] = f2h(W[k * 128 + n]);
}

// wcat_t[l][p][k], physical column p:
//   p in [0,128)   : gr = Wg[l][k][p]            bias bg[l][p]
//   p in [128,384) : j=(p-128)>>1
//       even       : gs = Wg[l][128+k][j]        bias 0
//       odd        : sv = Ws[l][k][j]            bias bs[l][j]
//   p in [384,512) : r  = Wr[l][k][p-384]        bias br[l][p-384]
__global__ void build_wcat(const float* __restrict__ Wg, const float* __restrict__ Ws,
                           const float* __restrict__ Wr, const float* __restrict__ bg,
                           const float* __restrict__ bs, const float* __restrict__ br,
                           ushort_t* __restrict__ Wt, float* __restrict__ bcat)
{
    int t = blockIdx.x * blockDim.x + threadIdx.x;   // t = ((l*512)+p)*128 + k
    if (t >= NLAYERS * 512 * 128) return;
    int l = t >> 16;
    int r = t & 65535;
    int p = r >> 7;
    int k = r & 127;
    float v, b;
    if (p < 128)      { v = Wg[l * 32768 + k * 128 + p];            b = bg[l * 128 + p]; }
    else if (p < 384) {
        int j = (p - 128) >> 1;
        if (((p - 128) & 1) == 0) { v = Wg[l * 32768 + (128 + k) * 128 + j]; b = 0.f; }
        else                      { v = Ws[l * 16384 + k * 128 + j];         b = bs[l * 128 + j]; }
    }
    else              { v = Wr[l * 16384 + k * 128 + (p - 384)];    b = br[l * 128 + (p - 384)]; }
    Wt[t] = f2h(v);
    if (k == 0) bcat[l * 512 + p] = b;
}

__global__ __launch_bounds__(256) void cast_f16(const float* __restrict__ src,
                                                ushort_t* __restrict__ dst, int n)
{
    int t = blockIdx.x * blockDim.x + threadIdx.x;
    if (t < n) dst[t] = f2h(src[t]);
}

// ------------------------------------------------------------------
// CSR build (by receiver): histogram -> exclusive scan -> scatter
// ------------------------------------------------------------------
__global__ __launch_bounds__(256) void hist_kernel(const int* __restrict__ ei,
                                                   int* __restrict__ cnt)
{
    int e = blockIdx.x * blockDim.x + threadIdx.x;
    if (e < N_EDGES) atomicAdd(&cnt[ei[N_EDGES + e]], 1);
}

__global__ __launch_bounds__(1024) void scan_kernel(const int* __restrict__ cnt,
                                                    int* __restrict__ off)
{
    __shared__ int wsum[16];
    __shared__ int s_running;
    int tid = threadIdx.x;
    int lane = tid & 63, wid = tid >> 6;
    if (tid == 0) { s_running = 0; off[0] = 0; }
    __syncthreads();
    for (int base = 0; base < N_NODES; base += 4096) {
        int i0 = base + tid * 4;
        int v[4];
#pragma unroll
        for (int u = 0; u < 4; u++) v[u] = (i0 + u < N_NODES) ? cnt[i0 + u] : 0;
        int tsum = v[0] + v[1] + v[2] + v[3];
        int x = tsum;
#pragma unroll
        for (int ofs = 1; ofs < 64; ofs <<= 1) {
            int y = __shfl_up(x, ofs);
            if (lane >= ofs) x += y;
        }
        if (lane == 63) wsum[wid] = x;
        __syncthreads();
        if (wid == 0) {
            int w = (lane < 16) ? wsum[lane] : 0;
#pragma unroll
            for (int ofs = 1; ofs < 16; ofs <<= 1) {
                int y = __shfl_up(w, ofs);
                if (lane >= ofs) w += y;
            }
            if (lane < 16) wsum[lane] = w;
        }
        __syncthreads();
        int wbase = (wid > 0) ? wsum[wid - 1] : 0;
        int excl = s_running + wbase + x - tsum;
        int run_total = s_running + wsum[15];
        __syncthreads();
#pragma unroll
        for (int u = 0; u < 4; u++) {
            excl += v[u];
            if (i0 + u < N_NODES) off[i0 + u + 1] = excl;
        }
        if (tid == 0) s_running = run_total;
        __syncthreads();
    }
}

__global__ __launch_bounds__(256) void scatter_kernel(const int* __restrict__ ei,
                                                      const int* __restrict__ off,
                                                      int* __restrict__ cur,
                                                      int* __restrict__ csr_send)
{
    int e = blockIdx.x * blockDim.x + threadIdx.x;
    if (e >= N_EDGES) return;
    int rec = ei[N_EDGES + e];
    int pos = off[rec] + atomicAdd(&cur[rec], 1);
    csr_send[pos] = ei[e];
}

// ------------------------------------------------------------------
// Node-centric aggregation + fused residual update (fp16 payloads).
// bigmid[n][2j]=gs[n][j], bigmid[n][2j+1]=sv[n][j]; gr16/r16 fp16.
// ------------------------------------------------------------------
__device__ __forceinline__ float gate_msg(uint_t pk, float gr) {
    float gs = h2f((ushort_t)(pk & 0xffff));
    float sv = h2f((ushort_t)(pk >> 16));
    return sv / (1.f + __expf(-(gr + gs)));
}

__global__ __launch_bounds__(128) void agg_kernel(
    const int* __restrict__ off, const int* __restrict__ csr_send,
    const ushort_t* __restrict__ bigmid, const ushort_t* __restrict__ gr16,
    const ushort_t* __restrict__ r16, float* __restrict__ h,
    ushort_t* __restrict__ h16)
{
    int n = blockIdx.x;
    int j = threadIdx.x;
    int p  = off[n];
    int p1 = off[n + 1];
    float gr  = h2f(gr16[(size_t)n * 128 + j]);
    float acc = h2f(r16[(size_t)n * 128 + j]);
    for (; p + 3 < p1; p += 4) {
        int s0 = csr_send[p + 0];
        int s1 = csr_send[p + 1];
        int s2 = csr_send[p + 2];
        int s3 = csr_send[p + 3];
        uint_t q0 = *(const uint_t*)(bigmid + (size_t)s0 * 256 + 2 * j);
        uint_t q1 = *(const uint_t*)(bigmid + (size_t)s1 * 256 + 2 * j);
        uint_t q2 = *(const uint_t*)(bigmid + (size_t)s2 * 256 + 2 * j);
        uint_t q3 = *(const uint_t*)(bigmid + (size_t)s3 * 256 + 2 * j);
        acc += gate_msg(q0, gr);
        acc += gate_msg(q1, gr);
        acc += gate_msg(q2, gr);
        acc += gate_msg(q3, gr);
    }
    for (; p < p1; p++) {
        int s0 = csr_send[p];
        uint_t q0 = *(const uint_t*)(bigmid + (size_t)s0 * 256 + 2 * j);
        acc += gate_msg(q0, gr);
    }
    float hn = h[(size_t)n * 128 + j] + fmaxf(acc, 0.f);
    h[(size_t)n * 128 + j] = hn;
    h16[(size_t)n * 128 + j] = f2h(hn);
}

// ------------------------------------------------------------------
// Pool: batch sorted -> contiguous range per graph.
// ------------------------------------------------------------------
__global__ __launch_bounds__(128) void pool_kernel(
    const float* __restrict__ h, const int* __restrict__ batch,
    float* __restrict__ hagg)
{
    int g = blockIdx.x;
    __shared__ int s_lo, s_hi;
    if (threadIdx.x == 0) {
        int lo = 0, hi = N_NODES;
        while (lo < hi) { int mid = (lo + hi) >> 1; if (batch[mid] < g) lo = mid + 1; else hi = mid; }
        s_lo = lo;
        hi = N_NODES;
        while (lo < hi) { int mid = (lo + hi) >> 1; if (batch[mid] < g + 1) lo = mid + 1; else hi = mid; }
        s_hi = lo;
    }
    __syncthreads();
    float acc = 0.f;
    int n = s_lo;
    for (; n + 1 < s_hi; n += 2)
        acc += h[(size_t)n * 128 + threadIdx.x] + h[(size_t)(n + 1) * 128 + threadIdx.x];
    if (n < s_hi) acc += h[(size_t)n * 128 + threadIdx.x];
    hagg[(size_t)g * 128 + threadIdx.x] = acc;
}

// ------------------------------------------------------------------
// Head: out[g] = relu(hagg[g] @ W1 + b1) @ W2 + b2
// ------------------------------------------------------------------
__global__ __launch_bounds__(64) void head_kernel(
    const float* __restrict__ hagg, const float* __restrict__ W1,
    const float* __restrict__ b1, const float* __restrict__ W2,
    const float* __restrict__ b2, float* __restrict__ out)
{
    int g = blockIdx.x;
    int j = threadIdx.x;
    float acc = b1[j];
    for (int k = 0; k < 128; k++)
        acc += hagg[(size_t)g * 128 + k] * W1[k * 64 + j];
    float val = fmaxf(acc, 0.f) * W2[j];
#pragma unroll
    for (int off = 32; off > 0; off >>= 1)
        val += __shfl_down(val, off);
    if (j == 0) out[g] = val + b2[0];
}

// ------------------------------------------------------------------
extern "C" void kernel_launch(void* const* d_in, const int* in_sizes, int n_in,
                              void* d_out, int out_size, void* d_ws, size_t ws_size,
                              hipStream_t stream) {
    const float* h_in    = (const float*)d_in[0];
    const int*   ei      = (const int*)d_in[1];
    const int*   batch   = (const int*)d_in[2];
    const float* W_embed = (const float*)d_in[3];
    const float* b_embed = (const float*)d_in[4];
    const float* Wg      = (const float*)d_in[5];
    const float* bg      = (const float*)d_in[6];
    const float* Ws      = (const float*)d_in[7];
    const float* bs      = (const float*)d_in[8];
    const float* Wr      = (const float*)d_in[9];
    const float* br      = (const float*)d_in[10];
    const float* W1      = (const float*)d_in[11];
    const float* b1      = (const float*)d_in[12];
    const float* W2      = (const float*)d_in[13];
    const float* b2      = (const float*)d_in[14];
    float* out = (float*)d_out;

    // workspace layout (fp32 first, then fp16, then ints)
    float* ws = (float*)d_ws;
    float*    h     = ws;                                    // N*128 f32
    float*    hagg  = h + (size_t)N_NODES * 128;             // G*128 f32
    float*    bcat  = hagg + NGRAPH * 128;                   // 4*512 f32
    ushort_t* a16   = (ushort_t*)(bcat + NLAYERS * 512);     // N*128 fp16
    ushort_t* h16   = a16 + (size_t)N_NODES * 128;           // N*128
    ushort_t* gr16  = h16 + (size_t)N_NODES * 128;           // N*128
    ushort_t* r16   = gr16 + (size_t)N_NODES * 128;          // N*128
    ushort_t* bigmid= r16 + (size_t)N_NODES * 128;           // N*256 fp16
    ushort_t* wet   = bigmid + (size_t)N_NODES * 256;        // 128*128
    ushort_t* wct   = wet + 128 * 128;                       // 4*512*128
    int* cnt      = (int*)(wct + NLAYERS * 512 * 128);       // N
    int* cur      = cnt + N_NODES;                           // N
    int* off      = cur + N_NODES;                           // N+1
    int* csr_send = off + N_NODES + 1;                       // E

    // CSR build
    hipMemsetAsync(cnt, 0, (size_t)2 * N_NODES * sizeof(int), stream);
    hist_kernel<<<(N_EDGES + 255) / 256, 256, 0, stream>>>(ei, cnt);
    scan_kernel<<<1, 1024, 0, stream>>>(cnt, off);
    scatter_kernel<<<(N_EDGES + 255) / 256, 256, 0, stream>>>(ei, off, cur, csr_send);

    // weight panels
    build_wembed<<<(128 * 128 + 255) / 256, 256, 0, stream>>>(W_embed, wet);
    build_wcat<<<(NLAYERS * 512 * 128 + 255) / 256, 256, 0, stream>>>(
        Wg, Ws, Wr, bg, bs, br, wct, bcat);

    // embed: h = h_in @ W_embed + b_embed
    cast_f16<<<((N_NODES * 128) + 255) / 256, 256, 0, stream>>>(h_in, a16, N_NODES * 128);
    {
        dim3 grid(768, 1);
        mfma_gemm_f16<<<grid, 128, 0, stream>>>(a16, wet, b_embed, N_NODES, 0,
                                                h, h16, nullptr, nullptr, nullptr);
    }

    for (int l = 0; l < NLAYERS; l++) {
        dim3 grid(384, 2);
        mfma_gemm_f16<<<grid, 256, 0, stream>>>(h16, wct + (size_t)l * 512 * 128,
                                                bcat + l * 512, N_NODES, 1,
                                                nullptr, nullptr, gr16, bigmid, r16);
        agg_kernel<<<N_NODES, 128, 0, stream>>>(off, csr_send, bigmid, gr16, r16, h, h16);
    }

    pool_kernel<<<NGRAPH, 128, 0, stream>>>(h, batch, hagg);
    head_kernel<<<NGRAPH, 64, 0, stream>>>(hagg, W1, b1, W2, b2, out);
}